// Round 2
// baseline (117.890 us; speedup 1.0000x reference)
//
#include <hip/hip_runtime.h>

#define NQ 10
#define TS 10
#define DIM 1024
#define ND 1024
#define WPS 2    // waves per sample
#define RPT 8    // DIM / (64 * WPS) amplitudes per lane

// One sample per block; block = 2 waves (128 threads). Wave w, lane L holds
// amplitudes idx = w*512 + r*64 + L, r = 0..7.
//   qubit 0  -> idx bit 9 = w      : cross-wave via LDS (double-buffered, 1 barrier/t-step)
//   qubits 1-3 -> idx bits 8..6 = r: in-thread register pairs
//   qubits 4-9 -> idx bits 5..0 = L: __shfl_xor
__global__ __launch_bounds__(128) void qsim_kernel(
    const float* __restrict__ re_in, const float* __restrict__ im_in,
    const float* __restrict__ phis, const float* __restrict__ gs,
    float* __restrict__ out)
{
    __shared__ float sre[2][DIM];
    __shared__ float sim_[2][DIM];

    const int sample = blockIdx.x;
    const int tid  = threadIdx.x;
    const int w    = tid >> 6;
    const int lane = tid & 63;
    const int half = w * (DIM / 2);          // 0 or 512

    const float* pr_in = re_in + sample * DIM + half;
    const float* pi_in = im_in + sample * DIM + half;

    float pr[RPT], pim[RPT];
#pragma unroll
    for (int r = 0; r < RPT; ++r) {
        pr[r]  = pr_in[r * 64 + lane];
        pim[r] = pi_in[r * 64 + lane];
    }

    // ---- normalize over the sample's 1024 amplitudes (cross-wave) ----
    float nrm = 0.f;
#pragma unroll
    for (int r = 0; r < RPT; ++r) nrm += pr[r] * pr[r] + pim[r] * pim[r];
#pragma unroll
    for (int off = 32; off >= 1; off >>= 1) nrm += __shfl_xor(nrm, off, 64);
    if (lane == 0) sre[0][w] = nrm;
    __syncthreads();
    const float scl = rsqrtf(sre[0][0] + sre[0][1]);
    __syncthreads();   // protect sre[0] before tt=0 exchange overwrites it
#pragma unroll
    for (int r = 0; r < RPT; ++r) { pr[r] *= scl; pim[r] *= scl; }

    // ---- pairsum per amplitude: 0.5*((10-2*popc(idx))^2 - 10) ----
    float ps[RPT];
#pragma unroll
    for (int r = 0; r < RPT; ++r) {
        const int idx = half + r * 64 + lane;
        const int zs = NQ - 2 * __popc(idx);
        ps[r] = 0.5f * (float)(zs * zs - NQ);
    }

    const float* ph = phis + sample * (3 * NQ * TS);
    const float inv = 0.15811388300841897f;  // 1/(2*sqrt(10))
    const float wsgn = w ? 1.f : -1.f;       // hi/lo half sign for cross-wave gate
    const int mypos   = half + /*r*64+lane added per r*/ lane;
    const int partpos = (half ^ (DIM / 2)) + lane;

    for (int tt = 0; tt < TS; ++tt) {
        const int base = 3 * NQ * tt;

        // ---------- qubit 0 (bit 9): cross-wave via LDS ----------
        {
            const float a  = ph[base + 0];
            const float th = ph[base + NQ + 0];
            const float b  = ph[base + 2 * NQ + 0];
            float c, s, cp, sp, cm, sm;
            __sincosf(0.5f * th,      &s,  &c);
            __sincosf(0.5f * (a + b), &sp, &cp);
            __sincosf(0.5f * (a - b), &sm, &cm);
            const float A = c * cp, B = c * sp, C = s * cm, D = s * sm;
            const float ownI = wsgn * B, partR = wsgn * C;

            const int d = tt & 1;
#pragma unroll
            for (int r = 0; r < RPT; ++r) {
                sre[d][mypos + r * 64]  = pr[r];
                sim_[d][mypos + r * 64] = pim[r];
            }
            __syncthreads();
#pragma unroll
            for (int r = 0; r < RPT; ++r) {
                const float qr = sre[d][partpos + r * 64];
                const float qi = sim_[d][partpos + r * 64];
                const float orr = pr[r], oi = pim[r];
                pr[r]  = A * orr - ownI * oi + partR * qr + D * qi;
                pim[r] = A * oi  + ownI * orr + partR * qi - D * qr;
            }
        }

        // ---------- qubits 1..9 ----------
#pragma unroll
        for (int i = 1; i < NQ; ++i) {
            const float a  = ph[base + i];
            const float th = ph[base + NQ + i];
            const float b  = ph[base + 2 * NQ + i];
            float c, s, cp, sp, cm, sm;
            __sincosf(0.5f * th,      &s,  &c);
            __sincosf(0.5f * (a + b), &sp, &cp);
            __sincosf(0.5f * (a - b), &sm, &cm);
            // M00=(A,-B)  M01=(-C,-D)  M10=(C,-D)  M11=(A,B)
            const float A = c * cp, B = c * sp, C = s * cm, D = s * sm;

            const int bitpos = NQ - 1 - i;  // 8..0
            if (bitpos >= 6) {
                const int rb = bitpos - 6;  // 2..0
#pragma unroll
                for (int r0 = 0; r0 < RPT; ++r0) {
                    if ((r0 >> rb) & 1) continue;
                    const int r1 = r0 | (1 << rb);
                    const float x0r = pr[r0], x0i = pim[r0];
                    const float x1r = pr[r1], x1i = pim[r1];
                    pr[r0]  = A * x0r + B * x0i - C * x1r + D * x1i;
                    pim[r0] = A * x0i - B * x0r - C * x1i - D * x1r;
                    pr[r1]  = C * x0r + D * x0i + A * x1r - B * x1i;
                    pim[r1] = C * x0i - D * x0r + A * x1i + B * x1r;
                }
            } else {
                const int mask = 1 << bitpos;
                const float sgn = (lane & mask) ? 1.f : -1.f;
                const float ownI  = sgn * B;
                const float partR = sgn * C;
#pragma unroll
                for (int r = 0; r < RPT; ++r) {
                    const float qr = __shfl_xor(pr[r],  mask, 64);
                    const float qi = __shfl_xor(pim[r], mask, 64);
                    const float orr = pr[r], oi = pim[r];
                    pr[r]  = A * orr - ownI * oi + partR * qr + D * qi;
                    pim[r] = A * oi  + ownI * orr + partR * qi - D * qr;
                }
            }
        }

        // ---------- diagonal phase ----------
        const float theta = gs[sample * TS + tt] * inv;
        const float k = -0.5f * theta;
#pragma unroll
        for (int r = 0; r < RPT; ++r) {
            float sa, ca;
            __sincosf(k * ps[r], &sa, &ca);
            const float xr = pr[r], xi = pim[r];
            pr[r]  = xr * ca - xi * sa;
            pim[r] = xr * sa + xi * ca;
        }
    }

    float* outr = out + sample * DIM + half;
    float* outi = out + ND * DIM + sample * DIM + half;
#pragma unroll
    for (int r = 0; r < RPT; ++r) {
        outr[r * 64 + lane] = pr[r];
        outi[r * 64 + lane] = pim[r];
    }
}

extern "C" void kernel_launch(void* const* d_in, const int* in_sizes, int n_in,
                              void* d_out, int out_size, void* d_ws, size_t ws_size,
                              hipStream_t stream) {
    const float* re_in = (const float*)d_in[0];
    const float* im_in = (const float*)d_in[1];
    const float* phis  = (const float*)d_in[2];
    const float* gs    = (const float*)d_in[3];
    float* out = (float*)d_out;
    qsim_kernel<<<ND, 128, 0, stream>>>(re_in, im_in, phis, gs, out);
}

// Round 3
// 108.540 us; speedup vs baseline: 1.0861x; 1.0861x over previous
//
#include <hip/hip_runtime.h>

#define NQ 10
#define TS 10
#define DIM 1024
#define ND 1024
#define RPT 16   // DIM / 64 amplitudes per lane

// One wave (64 lanes) per sample, full state in registers (64 x 16 = 1024).
// idx = r*64 + lane. Qubit i acts on idx bit (9-i):
//   bits 6..9 -> register pairs (in-thread), bits 0..5 -> __shfl_xor.
// All gate coefficients precomputed lane-parallel into LDS at kernel start;
// diagonal phase uses the 6-distinct-pairsum-value table.
__global__ __launch_bounds__(64) void qsim_kernel(
    const float* __restrict__ re_in, const float* __restrict__ im_in,
    const float* __restrict__ phis, const float* __restrict__ gs,
    float* __restrict__ out)
{
    __shared__ float4 gcoef[TS * NQ];   // (A,B,C,D) per gate, 1600 B
    __shared__ float2 dcoef[TS][6];     // (cos,sin) per step per popc-class, 480 B

    const int sample = blockIdx.x;
    const int lane = threadIdx.x;

    // ---- issue state loads early (long latency, overlapped with precompute) ----
    const float* pr_in = re_in + sample * DIM;
    const float* pi_in = im_in + sample * DIM;
    float pr[RPT], pim[RPT];
#pragma unroll
    for (int r = 0; r < RPT; ++r) {
        pr[r]  = pr_in[r * 64 + lane];
        pim[r] = pi_in[r * 64 + lane];
    }

    // ---- lane-parallel gate-coefficient precompute (100 gates over 64 lanes) ----
    const float* ph = phis + sample * (3 * NQ * TS);
#pragma unroll
    for (int rep = 0; rep < 2; ++rep) {
        const int g = lane + rep * 64;
        if (g < TS * NQ) {
            const int tt = g / 10;
            const int i  = g - tt * 10;
            const int base = 30 * tt;
            const float a  = ph[base + i];
            const float th = ph[base + 10 + i];
            const float b  = ph[base + 20 + i];
            float c, s, cp, sp, cm, sm;
            __sincosf(0.5f * th,      &s,  &c);
            __sincosf(0.5f * (a + b), &sp, &cp);
            __sincosf(0.5f * (a - b), &sm, &cm);
            gcoef[g] = make_float4(c * cp, c * sp, s * cm, s * sm);
        }
    }
    // ---- diagonal-phase table: 10 steps x 6 popc-classes, one sincos per lane ----
    if (lane < TS * 6) {
        const int tt = lane / 6;
        const int c  = lane - tt * 6;
        const float theta = gs[sample * TS + tt] * 0.15811388300841897f; // *1/(2*sqrt(10))
        const float k = -0.5f * theta;
        const int zs = NQ - 2 * c;          // class c corresponds to popc==c
        const float v = 0.5f * (float)(zs * zs - NQ);
        float sa, ca;
        __sincosf(k * v, &sa, &ca);
        dcoef[tt][c] = make_float2(ca, sa);
    }
    __syncthreads();   // single wave, but guarantees LDS writes visible

    // ---- normalize ----
    float nrm = 0.f;
#pragma unroll
    for (int r = 0; r < RPT; ++r) nrm += pr[r] * pr[r] + pim[r] * pim[r];
#pragma unroll
    for (int off = 32; off >= 1; off >>= 1) nrm += __shfl_xor(nrm, off, 64);
    const float scl = rsqrtf(nrm);
#pragma unroll
    for (int r = 0; r < RPT; ++r) { pr[r] *= scl; pim[r] *= scl; }

    // ---- popc class per register (for diagonal phase) ----
    int cls[RPT];
#pragma unroll
    for (int r = 0; r < RPT; ++r) {
        const int idx = r * 64 + lane;
        const int p = __popc(idx);
        cls[r] = (p <= 5) ? p : (10 - p);
    }

    for (int tt = 0; tt < TS; ++tt) {
        const float4* gc = &gcoef[tt * NQ];
#pragma unroll
        for (int i = 0; i < NQ; ++i) {
            const float4 m = gc[i];          // broadcast ds_read_b128
            const float A = m.x, B = m.y, C = m.z, D = m.w;
            // M00=(A,-B)  M01=(-C,-D)  M10=(C,-D)  M11=(A,B)
            const int bitpos = NQ - 1 - i;   // 9..0
            if (bitpos >= 6) {
                const int rb = bitpos - 6;
#pragma unroll
                for (int r0 = 0; r0 < RPT; ++r0) {
                    if ((r0 >> rb) & 1) continue;
                    const int r1 = r0 | (1 << rb);
                    const float x0r = pr[r0], x0i = pim[r0];
                    const float x1r = pr[r1], x1i = pim[r1];
                    pr[r0]  = A * x0r + B * x0i - C * x1r + D * x1i;
                    pim[r0] = A * x0i - B * x0r - C * x1i - D * x1r;
                    pr[r1]  = C * x0r + D * x0i + A * x1r - B * x1i;
                    pim[r1] = C * x0i - D * x0r + A * x1i + B * x1r;
                }
            } else {
                const int mask = 1 << bitpos;
                const float sgn = (lane & mask) ? 1.f : -1.f;
                const float ownI  = sgn * B;
                const float partR = sgn * C;
                // batch ALL shuffles first, then the math (hide ds latency)
                float qr[RPT], qi[RPT];
#pragma unroll
                for (int r = 0; r < RPT; ++r) {
                    qr[r] = __shfl_xor(pr[r],  mask, 64);
                    qi[r] = __shfl_xor(pim[r], mask, 64);
                }
#pragma unroll
                for (int r = 0; r < RPT; ++r) {
                    const float orr = pr[r], oi = pim[r];
                    pr[r]  = A * orr - ownI * oi + partR * qr[r] + D * qi[r];
                    pim[r] = A * oi  + ownI * orr + partR * qi[r] - D * qr[r];
                }
            }
        }
        // ---- diagonal phase: batched table reads, then rotate ----
        float2 e[RPT];
#pragma unroll
        for (int r = 0; r < RPT; ++r) e[r] = dcoef[tt][cls[r]];
#pragma unroll
        for (int r = 0; r < RPT; ++r) {
            const float xr = pr[r], xi = pim[r];
            pr[r]  = xr * e[r].x - xi * e[r].y;
            pim[r] = xr * e[r].y + xi * e[r].x;
        }
    }

#pragma unroll
    for (int r = 0; r < RPT; ++r) {
        out[sample * DIM + r * 64 + lane]            = pr[r];
        out[ND * DIM + sample * DIM + r * 64 + lane] = pim[r];
    }
}

extern "C" void kernel_launch(void* const* d_in, const int* in_sizes, int n_in,
                              void* d_out, int out_size, void* d_ws, size_t ws_size,
                              hipStream_t stream) {
    const float* re_in = (const float*)d_in[0];
    const float* im_in = (const float*)d_in[1];
    const float* phis  = (const float*)d_in[2];
    const float* gs    = (const float*)d_in[3];
    float* out = (float*)d_out;
    qsim_kernel<<<ND, 64, 0, stream>>>(re_in, im_in, phis, gs, out);
}

// Round 4
// 100.659 us; speedup vs baseline: 1.1712x; 1.0783x over previous
//
#include <hip/hip_runtime.h>

#define NQ 10
#define TS 10
#define DIM 1024
#define ND 1024
#define NK 8     // 8 float2 pairs = 16 amplitudes per lane

typedef float f2 __attribute__((ext_vector_type(2)));

// One wave (64 lanes) per sample, full state in registers, ZERO LDS.
// idx = r*64 + lane, r = 2k + j (k=0..7, j=0..1). State packed as float2
// over j? No: packed over r-pairs: PR[k] = (re[r=2k], re[r=2k+1]).
//   qubit 0 -> idx bit 9 = k bit 2 : float2-uniform register pairs (pk math)
//   qubit 1 -> idx bit 8 = k bit 1 : same
//   qubit 2 -> idx bit 7 = k bit 0 : same
//   qubit 3 -> idx bit 6 = j       : within-float2 (swizzle + per-half coeffs)
//   qubits 4..9 -> lane bits 5..0  : __shfl_xor (batched) + pk math
// All coefficients computed inline on VALU (wave-uniform); phis bulk-loaded
// per t-step to avoid per-gate load latency.

template <int RB>
__device__ __forceinline__ void gate_k(f2* PR, f2* PI,
                                       float A, float B, float C, float D) {
#pragma unroll
    for (int k0 = 0; k0 < NK; ++k0) {
        if (k0 & (1 << RB)) continue;
        const int k1 = k0 | (1 << RB);
        const f2 x0r = PR[k0], x0i = PI[k0];
        const f2 x1r = PR[k1], x1i = PI[k1];
        PR[k0] = A * x0r + B * x0i - C * x1r + D * x1i;
        PI[k0] = A * x0i - B * x0r - C * x1i - D * x1r;
        PR[k1] = C * x0r + D * x0i + A * x1r - B * x1i;
        PI[k1] = C * x0i - D * x0r + A * x1i + B * x1r;
    }
}

__device__ __forceinline__ void gate_j(f2* PR, f2* PI,
                                       float A, float B, float C, float D) {
    const f2 AC   = {A, C},  BD  = {B, D};
    const f2 mCA  = {-C, A}, DmB = {D, -B};
    const f2 mBmD = {-B, -D}, mDB = {-D, B};
#pragma unroll
    for (int k = 0; k < NK; ++k) {
        const f2 rx = PR[k].xx, ry = PR[k].yy;
        const f2 ix = PI[k].xx, iy = PI[k].yy;
        PR[k] = AC * rx + BD * ix + mCA * ry + DmB * iy;
        PI[k] = AC * ix + mBmD * rx + mCA * iy + mDB * ry;
    }
}

template <int MASK>
__device__ __forceinline__ void gate_lane(int lane, f2* PR, f2* PI,
                                          float A, float B, float C, float D) {
    const float sgn = (lane & MASK) ? 1.f : -1.f;
    const float ownI = sgn * B;   // own coeff  = (A, ownI)
    const float partR = sgn * C;  // part coeff = (partR, -D)
    f2 qR[NK], qI[NK];
#pragma unroll
    for (int k = 0; k < NK; ++k) {   // batch ALL shuffles first
        qR[k].x = __shfl_xor(PR[k].x, MASK, 64);
        qR[k].y = __shfl_xor(PR[k].y, MASK, 64);
        qI[k].x = __shfl_xor(PI[k].x, MASK, 64);
        qI[k].y = __shfl_xor(PI[k].y, MASK, 64);
    }
#pragma unroll
    for (int k = 0; k < NK; ++k) {
        const f2 orr = PR[k], oi = PI[k];
        PR[k] = A * orr - ownI * oi + partR * qR[k] + D * qI[k];
        PI[k] = A * oi + ownI * orr + partR * qI[k] - D * qR[k];
    }
}

__global__ __launch_bounds__(64) void qsim_kernel(
    const float* __restrict__ re_in, const float* __restrict__ im_in,
    const float* __restrict__ phis, const float* __restrict__ gs,
    float* __restrict__ out)
{
    const int sample = blockIdx.x;
    const int lane = threadIdx.x;

    const float* pr_in = re_in + sample * DIM;
    const float* pi_in = im_in + sample * DIM;

    f2 PR[NK], PI[NK];
#pragma unroll
    for (int k = 0; k < NK; ++k) {
        PR[k].x = pr_in[(2 * k) * 64 + lane];
        PR[k].y = pr_in[(2 * k + 1) * 64 + lane];
        PI[k].x = pi_in[(2 * k) * 64 + lane];
        PI[k].y = pi_in[(2 * k + 1) * 64 + lane];
    }

    // bulk-load all gs (scaled) up front
    const float inv = 0.15811388300841897f;  // 1/(2*sqrt(10))
    float gl[TS];
#pragma unroll
    for (int t = 0; t < TS; ++t) gl[t] = gs[sample * TS + t] * inv;

    // ---- normalize ----
    f2 n2 = {0.f, 0.f};
#pragma unroll
    for (int k = 0; k < NK; ++k) n2 += PR[k] * PR[k] + PI[k] * PI[k];
    float nrm = n2.x + n2.y;
#pragma unroll
    for (int off = 32; off >= 1; off >>= 1) nrm += __shfl_xor(nrm, off, 64);
    const float scl = rsqrtf(nrm);
#pragma unroll
    for (int k = 0; k < NK; ++k) { PR[k] *= scl; PI[k] *= scl; }

    // ---- pairsum per amplitude ----
    f2 PS[NK];
#pragma unroll
    for (int k = 0; k < NK; ++k) {
        const int i0 = (2 * k) * 64 + lane;
        const int i1 = (2 * k + 1) * 64 + lane;
        const int z0 = NQ - 2 * __popc(i0);
        const int z1 = NQ - 2 * __popc(i1);
        PS[k].x = 0.5f * (float)(z0 * z0 - NQ);
        PS[k].y = 0.5f * (float)(z1 * z1 - NQ);
    }

    const float* ph = phis + sample * (3 * NQ * TS);

    for (int tt = 0; tt < TS; ++tt) {
        // bulk-load this step's 30 phis (one latency exposure)
        float phs[30];
#pragma unroll
        for (int j = 0; j < 30; ++j) phs[j] = ph[30 * tt + j];

#define COEF(g)                                            \
        float A, B, C, D;                                  \
        {                                                  \
            const float a = phs[g], th = phs[10 + (g)],    \
                        b = phs[20 + (g)];                 \
            float c, s, cp, sp, cm, sm;                    \
            __sincosf(0.5f * th,      &s,  &c);            \
            __sincosf(0.5f * (a + b), &sp, &cp);           \
            __sincosf(0.5f * (a - b), &sm, &cm);           \
            A = c * cp; B = c * sp; C = s * cm; D = s * sm;\
        }

        { COEF(0) gate_k<2>(PR, PI, A, B, C, D); }        // qubit 0 (bit 9)
        { COEF(1) gate_k<1>(PR, PI, A, B, C, D); }        // qubit 1 (bit 8)
        { COEF(2) gate_k<0>(PR, PI, A, B, C, D); }        // qubit 2 (bit 7)
        { COEF(3) gate_j(PR, PI, A, B, C, D); }           // qubit 3 (bit 6)
        { COEF(4) gate_lane<32>(lane, PR, PI, A, B, C, D); } // qubit 4
        { COEF(5) gate_lane<16>(lane, PR, PI, A, B, C, D); } // qubit 5
        { COEF(6) gate_lane< 8>(lane, PR, PI, A, B, C, D); } // qubit 6
        { COEF(7) gate_lane< 4>(lane, PR, PI, A, B, C, D); } // qubit 7
        { COEF(8) gate_lane< 2>(lane, PR, PI, A, B, C, D); } // qubit 8
        { COEF(9) gate_lane< 1>(lane, PR, PI, A, B, C, D); } // qubit 9
#undef COEF

        // ---- diagonal phase (inline sincos, no LDS) ----
        const float kk = -0.5f * gl[tt];
#pragma unroll
        for (int k = 0; k < NK; ++k) {
            float sx, cx, sy, cy;
            __sincosf(kk * PS[k].x, &sx, &cx);
            __sincosf(kk * PS[k].y, &sy, &cy);
            const f2 CA = {cx, cy}, SA = {sx, sy};
            const f2 xr = PR[k], xi = PI[k];
            PR[k] = xr * CA - xi * SA;
            PI[k] = xr * SA + xi * CA;
        }
    }

    float* outr = out + sample * DIM;
    float* outi = out + ND * DIM + sample * DIM;
#pragma unroll
    for (int k = 0; k < NK; ++k) {
        outr[(2 * k) * 64 + lane]     = PR[k].x;
        outr[(2 * k + 1) * 64 + lane] = PR[k].y;
        outi[(2 * k) * 64 + lane]     = PI[k].x;
        outi[(2 * k + 1) * 64 + lane] = PI[k].y;
    }
}

extern "C" void kernel_launch(void* const* d_in, const int* in_sizes, int n_in,
                              void* d_out, int out_size, void* d_ws, size_t ws_size,
                              hipStream_t stream) {
    const float* re_in = (const float*)d_in[0];
    const float* im_in = (const float*)d_in[1];
    const float* phis  = (const float*)d_in[2];
    const float* gs    = (const float*)d_in[3];
    float* out = (float*)d_out;
    qsim_kernel<<<ND, 64, 0, stream>>>(re_in, im_in, phis, gs, out);
}

// Round 6
// 98.300 us; speedup vs baseline: 1.1993x; 1.0240x over previous
//
#include <hip/hip_runtime.h>

#define NQ 10
#define TS 10
#define DIM 1024
#define ND 1024
#define NK 8     // 8 float2 pairs = 16 amplitudes per lane

typedef float f2 __attribute__((ext_vector_type(2)));

// ---------- full-rate cross-lane exchange via DPP (no DS pipe) ----------
// Direction convention (per LLVM AMDGPUAtomicOptimizer::buildScan):
//   row_shr:n -> dst[i] = src[i-n]   (0x110 | n)
//   row_shl:n -> dst[i] = src[i+n]   (0x100 | n)
template<int CTRL>
__device__ __forceinline__ float dpp_full(float x) {
    const int xi = __float_as_int(x);
    return __int_as_float(__builtin_amdgcn_update_dpp(xi, xi, CTRL, 0xF, 0xF, false));
}
__device__ __forceinline__ float dpp_xor4(float x) {
    const int xi = __float_as_int(x);
    // banks 0,2 (lane bit2=0) need src[i+4] -> row_shl:4 (0x104), bank_mask 0x5
    // banks 1,3 (lane bit2=1) need src[i-4] -> row_shr:4 (0x114), bank_mask 0xA
    int q = __builtin_amdgcn_update_dpp(0, xi, 0x104, 0xF, 0x5, false);
    q     = __builtin_amdgcn_update_dpp(q, xi, 0x114, 0xF, 0xA, false);
    return __int_as_float(q);
}
template<int MASK>
__device__ __forceinline__ float lshuf(float x) {
    if constexpr (MASK == 1)      return dpp_full<0xB1>(x);   // quad_perm [1,0,3,2]
    else if constexpr (MASK == 2) return dpp_full<0x4E>(x);   // quad_perm [2,3,0,1]
    else if constexpr (MASK == 4) return dpp_xor4(x);
    else if constexpr (MASK == 8) return dpp_full<0x128>(x);  // row_ror:8 == xor8
    else return __shfl_xor(x, MASK, 64);                      // 16, 32: ds path
}

// ---------- gates ----------
template <int RB>
__device__ __forceinline__ void gate_k(f2* PR, f2* PI,
                                       float A, float B, float C, float D) {
#pragma unroll
    for (int k0 = 0; k0 < NK; ++k0) {
        if (k0 & (1 << RB)) continue;
        const int k1 = k0 | (1 << RB);
        const f2 x0r = PR[k0], x0i = PI[k0];
        const f2 x1r = PR[k1], x1i = PI[k1];
        PR[k0] = A * x0r + B * x0i - C * x1r + D * x1i;
        PI[k0] = A * x0i - B * x0r - C * x1i - D * x1r;
        PR[k1] = C * x0r + D * x0i + A * x1r - B * x1i;
        PI[k1] = C * x0i - D * x0r + A * x1i + B * x1r;
    }
}

__device__ __forceinline__ void gate_j(f2* PR, f2* PI,
                                       float A, float B, float C, float D) {
    const f2 AC   = {A, C},  BD  = {B, D};
    const f2 mCA  = {-C, A}, DmB = {D, -B};
    const f2 mBmD = {-B, -D}, mDB = {-D, B};
#pragma unroll
    for (int k = 0; k < NK; ++k) {
        const f2 rx = PR[k].xx, ry = PR[k].yy;
        const f2 ix = PI[k].xx, iy = PI[k].yy;
        PR[k] = AC * rx + BD * ix + mCA * ry + DmB * iy;
        PI[k] = AC * ix + mBmD * rx + mCA * iy + mDB * ry;
    }
}

template <int MASK>
__device__ __forceinline__ void gate_lane(int lane, f2* PR, f2* PI,
                                          float A, float B, float C, float D) {
    const float sgn = (lane & MASK) ? 1.f : -1.f;
    const float ownI  = sgn * B;   // own coeff  = (A, ownI)
    const float partR = sgn * C;   // part coeff = (partR, -D)
    f2 qR[NK], qI[NK];
#pragma unroll
    for (int k = 0; k < NK; ++k) {   // batch all exchanges first
        qR[k].x = lshuf<MASK>(PR[k].x);
        qR[k].y = lshuf<MASK>(PR[k].y);
        qI[k].x = lshuf<MASK>(PI[k].x);
        qI[k].y = lshuf<MASK>(PI[k].y);
    }
#pragma unroll
    for (int k = 0; k < NK; ++k) {
        const f2 orr = PR[k], oi = PI[k];
        PR[k] = A * orr - ownI * oi + partR * qR[k] + D * qI[k];
        PI[k] = A * oi + ownI * orr + partR * qI[k] - D * qR[k];
    }
}

// One wave per sample, full state in registers, zero LDS, DS only for xor16/32.
// VGPRs are free (grid == SIMD count -> occupancy pinned at 1 wave/SIMD).
__global__ __launch_bounds__(64, 1) void qsim_kernel(
    const float* __restrict__ re_in, const float* __restrict__ im_in,
    const float* __restrict__ phis, const float* __restrict__ gs,
    float* __restrict__ out)
{
    const int sample = blockIdx.x;
    const int lane = threadIdx.x;

    const float* pr_in = re_in + sample * DIM;
    const float* pi_in = im_in + sample * DIM;

    f2 PR[NK], PI[NK];
#pragma unroll
    for (int k = 0; k < NK; ++k) {
        PR[k].x = pr_in[(2 * k) * 64 + lane];
        PR[k].y = pr_in[(2 * k + 1) * 64 + lane];
        PI[k].x = pi_in[(2 * k) * 64 + lane];
        PI[k].y = pi_in[(2 * k + 1) * 64 + lane];
    }

    const float inv = 0.15811388300841897f;  // 1/(2*sqrt(10))
    float gl[TS];
#pragma unroll
    for (int t = 0; t < TS; ++t) gl[t] = gs[sample * TS + t] * inv;

    // ---- normalize ----
    f2 n2 = {0.f, 0.f};
#pragma unroll
    for (int k = 0; k < NK; ++k) n2 += PR[k] * PR[k] + PI[k] * PI[k];
    float nrm = n2.x + n2.y;
#pragma unroll
    for (int off = 32; off >= 1; off >>= 1) nrm += __shfl_xor(nrm, off, 64);
    const float scl = rsqrtf(nrm);
#pragma unroll
    for (int k = 0; k < NK; ++k) { PR[k] *= scl; PI[k] *= scl; }

    // ---- pairsum per amplitude ----
    f2 PS[NK];
#pragma unroll
    for (int k = 0; k < NK; ++k) {
        const int i0 = (2 * k) * 64 + lane;
        const int i1 = (2 * k + 1) * 64 + lane;
        const int z0 = NQ - 2 * __popc(i0);
        const int z1 = NQ - 2 * __popc(i1);
        PS[k].x = 0.5f * (float)(z0 * z0 - NQ);
        PS[k].y = 0.5f * (float)(z1 * z1 - NQ);
    }

    const float* ph = phis + sample * (3 * NQ * TS);

    for (int tt = 0; tt < TS; ++tt) {
        // bulk-load this step's 30 phis (uniform -> SGPRs)
        float phs[30];
#pragma unroll
        for (int j = 0; j < 30; ++j) phs[j] = ph[30 * tt + j];

        // ---- ALL transcendentals for this step, hoisted & independent ----
        float GA[NQ], GB[NQ], GC[NQ], GD[NQ];
#pragma unroll
        for (int g = 0; g < NQ; ++g) {
            const float a = phs[g], th = phs[10 + g], b = phs[20 + g];
            float c, s, cp, sp, cm, sm;
            __sincosf(0.5f * th,      &s,  &c);
            __sincosf(0.5f * (a + b), &sp, &cp);
            __sincosf(0.5f * (a - b), &sm, &cm);
            GA[g] = c * cp; GB[g] = c * sp; GC[g] = s * cm; GD[g] = s * sm;
        }
        f2 DC[NK], DS_[NK];
        const float kk = -0.5f * gl[tt];
#pragma unroll
        for (int k = 0; k < NK; ++k) {
            float sx, cx, sy, cy;
            __sincosf(kk * PS[k].x, &sx, &cx);
            __sincosf(kk * PS[k].y, &sy, &cy);
            DC[k] = (f2){cx, cy};
            DS_[k] = (f2){sx, sy};
        }

        // ---- gates (M00=(A,-B) M01=(-C,-D) M10=(C,-D) M11=(A,B)) ----
        gate_k<2>(PR, PI, GA[0], GB[0], GC[0], GD[0]);            // qubit 0 (bit 9)
        gate_k<1>(PR, PI, GA[1], GB[1], GC[1], GD[1]);            // qubit 1 (bit 8)
        gate_k<0>(PR, PI, GA[2], GB[2], GC[2], GD[2]);            // qubit 2 (bit 7)
        gate_j   (PR, PI, GA[3], GB[3], GC[3], GD[3]);            // qubit 3 (bit 6)
        gate_lane<32>(lane, PR, PI, GA[4], GB[4], GC[4], GD[4]);  // qubit 4
        gate_lane<16>(lane, PR, PI, GA[5], GB[5], GC[5], GD[5]);  // qubit 5
        gate_lane< 8>(lane, PR, PI, GA[6], GB[6], GC[6], GD[6]);  // qubit 6 (DPP)
        gate_lane< 4>(lane, PR, PI, GA[7], GB[7], GC[7], GD[7]);  // qubit 7 (DPP)
        gate_lane< 2>(lane, PR, PI, GA[8], GB[8], GC[8], GD[8]);  // qubit 8 (DPP)
        gate_lane< 1>(lane, PR, PI, GA[9], GB[9], GC[9], GD[9]);  // qubit 9 (DPP)

        // ---- diagonal phase ----
#pragma unroll
        for (int k = 0; k < NK; ++k) {
            const f2 xr = PR[k], xi = PI[k];
            PR[k] = xr * DC[k] - xi * DS_[k];
            PI[k] = xr * DS_[k] + xi * DC[k];
        }
    }

    float* outr = out + sample * DIM;
    float* outi = out + ND * DIM + sample * DIM;
#pragma unroll
    for (int k = 0; k < NK; ++k) {
        outr[(2 * k) * 64 + lane]     = PR[k].x;
        outr[(2 * k + 1) * 64 + lane] = PR[k].y;
        outi[(2 * k) * 64 + lane]     = PI[k].x;
        outi[(2 * k + 1) * 64 + lane] = PI[k].y;
    }
}

extern "C" void kernel_launch(void* const* d_in, const int* in_sizes, int n_in,
                              void* d_out, int out_size, void* d_ws, size_t ws_size,
                              hipStream_t stream) {
    const float* re_in = (const float*)d_in[0];
    const float* im_in = (const float*)d_in[1];
    const float* phis  = (const float*)d_in[2];
    const float* gs    = (const float*)d_in[3];
    float* out = (float*)d_out;
    qsim_kernel<<<ND, 64, 0, stream>>>(re_in, im_in, phis, gs, out);
}